// Round 1
// baseline (500.000 us; speedup 1.0000x reference)
//
#include <hip/hip_runtime.h>
#include <math.h>

#define FEAT 64
#define NKERN 3

// Aggregate: g[n, k*64+j] = sum_{e in row(n)} w[e,k] * h[colind[e], j]
// One wave (64 lanes) per node. Lanes < deg compute their own edge's
// Gaussian kernel weights; edge loop broadcasts (c, w0..w2) via __shfl
// with a uniform index (-> v_readlane -> scalar base for the gather).
__global__ __launch_bounds__(256) void agg_kernel(
    const float* __restrict__ h,       // [N, 64]
    const float* __restrict__ pseudo,  // [E, 2]
    const int*   __restrict__ rowptr,  // [N+1]
    const int*   __restrict__ colind,  // [E]
    const float* __restrict__ projW,   // [2,2] this layer, row-major (din,dout)
    const float* __restrict__ projB,   // [2]
    const float* __restrict__ mu,      // [3,2]
    const float* __restrict__ isg,     // [3,2]
    float* __restrict__ g,             // [N, 192]
    int n_nodes)
{
    int lane = threadIdx.x & 63;
    int node = (int)((blockIdx.x * blockDim.x + threadIdx.x) >> 6);
    if (node >= n_nodes) return;
    int nu = __builtin_amdgcn_readfirstlane(node);
    int r0 = rowptr[nu];
    int r1 = rowptr[nu + 1];
    int deg = r1 - r0;   // fixed 32 in this problem; assume <= 64

    float w0 = 0.f, w1 = 0.f, w2 = 0.f;
    int c = 0;
    if (lane < deg) {
        int e = r0 + lane;
        float p0 = pseudo[2 * e];
        float p1 = pseudo[2 * e + 1];
        // u = tanh(p @ W + b); W row-major [din][dout]
        float u0 = tanhf(fmaf(p0, projW[0], fmaf(p1, projW[2], projB[0])));
        float u1 = tanhf(fmaf(p0, projW[1], fmaf(p1, projW[3], projB[1])));
        float d0, d1, s0, s1;
        d0 = u0 - mu[0]; d1 = u1 - mu[1]; s0 = isg[0]; s1 = isg[1];
        w0 = expf(-0.5f * (d0*d0*s0*s0 + d1*d1*s1*s1));
        d0 = u0 - mu[2]; d1 = u1 - mu[3]; s0 = isg[2]; s1 = isg[3];
        w1 = expf(-0.5f * (d0*d0*s0*s0 + d1*d1*s1*s1));
        d0 = u0 - mu[4]; d1 = u1 - mu[5]; s0 = isg[4]; s1 = isg[5];
        w2 = expf(-0.5f * (d0*d0*s0*s0 + d1*d1*s1*s1));
        c = colind[e];
    }

    float a0 = 0.f, a1 = 0.f, a2 = 0.f;
    for (int e = 0; e < deg; ++e) {
        int   cc  = __shfl(c, e);
        float ww0 = __shfl(w0, e);
        float ww1 = __shfl(w1, e);
        float ww2 = __shfl(w2, e);
        float v = h[(size_t)cc * FEAT + lane];   // coalesced 256B gather
        a0 = fmaf(ww0, v, a0);
        a1 = fmaf(ww1, v, a1);
        a2 = fmaf(ww2, v, a2);
    }
    float* gp = g + (size_t)node * (NKERN * FEAT);
    gp[lane]            = a0;
    gp[FEAT + lane]     = a1;
    gp[2 * FEAT + lane] = a2;
}

// out[n, f] = sum_{jp=0..191} g[n, jp] * Wcat[jp, f]
// where Wcat[k*64+j, f] = fc_W[j, k*64+f]. Wcat staged in LDS (48 KB).
// Each wave computes 4 rows; g reads are wave-uniform broadcasts.
__global__ __launch_bounds__(256) void gemm_kernel(
    const float* __restrict__ g,    // [N, 192]
    const float* __restrict__ fcW,  // [64, 192] this layer
    float* __restrict__ out,        // [N, 64]
    int n_nodes)
{
    __shared__ float Wl[192 * 64];  // 48 KB
    int tid = threadIdx.x;
    for (int idx = tid; idx < 192 * 64; idx += 256) {
        int jp = idx >> 6, f = idx & 63;
        int k = jp >> 6, j = jp & 63;
        Wl[idx] = fcW[j * 192 + k * 64 + f];
    }
    __syncthreads();

    int lane   = tid & 63;
    int gwave  = (int)((blockIdx.x * 256 + tid) >> 6);
    int nwave  = gridDim.x * 4;
    int nchunk = (n_nodes + 3) >> 2;

    for (int ch = gwave; ch < nchunk; ch += nwave) {
        int row0 = __builtin_amdgcn_readfirstlane(ch << 2);
        int nr = n_nodes - row0; if (nr > 4) nr = 4;
        const float* grow = g + (size_t)row0 * 192;
        if (nr == 4) {
            float acc0 = 0.f, acc1 = 0.f, acc2 = 0.f, acc3 = 0.f;
            #pragma unroll 8
            for (int j = 0; j < 192; ++j) {
                float wv = Wl[j * 64 + lane];     // stride 64: 2 lanes/bank, free
                acc0 = fmaf(grow[j],        wv, acc0);
                acc1 = fmaf(grow[192 + j],  wv, acc1);
                acc2 = fmaf(grow[384 + j],  wv, acc2);
                acc3 = fmaf(grow[576 + j],  wv, acc3);
            }
            out[(size_t)(row0    ) * 64 + lane] = acc0;
            out[(size_t)(row0 + 1) * 64 + lane] = acc1;
            out[(size_t)(row0 + 2) * 64 + lane] = acc2;
            out[(size_t)(row0 + 3) * 64 + lane] = acc3;
        } else {
            for (int r = 0; r < nr; ++r) {
                float acc = 0.f;
                for (int j = 0; j < 192; ++j)
                    acc = fmaf(grow[r * 192 + j], Wl[j * 64 + lane], acc);
                out[(size_t)(row0 + r) * 64 + lane] = acc;
            }
        }
    }
}

extern "C" void kernel_launch(void* const* d_in, const int* in_sizes, int n_in,
                              void* d_out, int out_size, void* d_ws, size_t ws_size,
                              hipStream_t stream)
{
    const float* feat   = (const float*)d_in[0];   // [N, 64]
    const float* pseudo = (const float*)d_in[1];   // [E, 2]
    const int*   rowptr = (const int*)d_in[2];     // [N+1]
    const int*   colind = (const int*)d_in[3];     // [E]
    const float* projW  = (const float*)d_in[4];   // [L, 2, 2]
    const float* projB  = (const float*)d_in[5];   // [L, 2]
    const float* fcW    = (const float*)d_in[6];   // [L, 64, 192]
    const float* mu     = (const float*)d_in[7];   // [L, 3, 2]
    const float* isg    = (const float*)d_in[8];   // [L, 3, 2]
    float* out = (float*)d_out;

    int n = in_sizes[0] / FEAT;                         // 50000
    int n_layers = in_sizes[6] / (FEAT * NKERN * FEAT); // 3

    float* gbuf = (float*)d_ws;                    // n * 192 floats
    float* hbuf = gbuf + (size_t)n * NKERN * FEAT; // n * 64 floats

    dim3 blk(256);
    dim3 aggGrid((n + 3) / 4);
    dim3 gemmGrid(1024);

    const float* hin = feat;
    for (int l = 0; l < n_layers; ++l) {
        float* hout = (l == n_layers - 1) ? out : hbuf;
        agg_kernel<<<aggGrid, blk, 0, stream>>>(
            hin, pseudo, rowptr, colind,
            projW + (size_t)l * 4, projB + (size_t)l * 2,
            mu + (size_t)l * 6, isg + (size_t)l * 6,
            gbuf, n);
        gemm_kernel<<<gemmGrid, blk, 0, stream>>>(
            gbuf, fcW + (size_t)l * FEAT * NKERN * FEAT, hout, n);
        hin = hbuf;
    }
}